// Round 8
// baseline (1128.113 us; speedup 1.0000x reference)
//
#include <hip/hip_runtime.h>

// ---------------- problem dims ----------------
#define IN_F  128
#define GHID  512
#define NHID  128
#define NTOK  196608L   // 1024 * 192

#define L2E 1.4426950408889634f

typedef __attribute__((ext_vector_type(8))) short short8;
typedef __attribute__((ext_vector_type(16))) float floatx16;
typedef __attribute__((ext_vector_type(4))) float f4;

// ---------------- ws layout ----------------
// bf16 packed weights (ushort elems), 32x32x16 A-fragment order:
//   frag index = ((gate*(H/32) + tn) * (K/16) + tk), 512 elems per frag,
//   elem (lane,j): n = tn*32 + (lane&31), k = tk*16 + (lane>>5)*8 + j
#define O_GW0 0L
#define O_GW1 196608L
#define O_GW2 983040L
#define O_NW0 1769472L
#define O_NW1 1818624L
#define NWS   1867776L
// fp32 region (float elems), base byte = NWS*2
#define F_GB0 0
#define F_GB1 1536
#define F_GB2 3072
#define F_NB0 4608
#define F_NB1 4992
#define F_WE  5376
#define F_AW  5888
#define F_BE  6016
#define F_AB  6017

__device__ __forceinline__ unsigned short f2bf(float f) {
  unsigned int u = __float_as_uint(f);
  u += 0x7fffu + ((u >> 16) & 1u);      // RNE
  return (unsigned short)(u >> 16);
}

// ---------------- prep kernel: repack weights (NO prescale — R6 lesson) ----
// R17: 32x32x16 A-frag permutation (same region sizes/offsets as 16x16).
__device__ __forceinline__ long srcoff(long pp, int H, int K) {
  long f = pp >> 9;
  int r = (int)(pp & 511);
  int ln = r >> 3, j = r & 7;
  int nKT = K >> 4, nCT = H >> 5;
  int tk = (int)(f % nKT);
  long t2 = f / nKT;
  int tn = (int)(t2 % nCT);
  int gate = (int)(t2 / nCT);
  int n = tn * 32 + (ln & 31);
  int k = tk * 16 + ((ln >> 5) << 3) + j;
  int go = (gate == 0) ? 0 : ((gate == 1) ? 2 * H : 3 * H);  // i, c, o rows
  return (long)(go + n) * K + k;
}

__global__ void prep_kernel(
    const float* __restrict__ gW0, const float* __restrict__ gbi0, const float* __restrict__ gbh0,
    const float* __restrict__ gW,  const float* __restrict__ gbi,  const float* __restrict__ gbh,
    const float* __restrict__ eW,  const float* __restrict__ eb,
    const float* __restrict__ nW0, const float* __restrict__ nbi0, const float* __restrict__ nbh0,
    const float* __restrict__ nW,  const float* __restrict__ nbi,  const float* __restrict__ nbh,
    const float* __restrict__ aW,  const float* __restrict__ ab,
    unsigned short* __restrict__ wpk, float* __restrict__ fpk)
{
  long idx = (long)blockIdx.x * blockDim.x + threadIdx.x;
  if (idx < NWS) {
    const float* src;
    long off;
    if (idx < O_GW1)      { off = srcoff(idx - O_GW0, 512, 128); src = gW0; }
    else if (idx < O_GW2) { off = srcoff(idx - O_GW1, 512, 512); src = gW; }
    else if (idx < O_NW0) { off = srcoff(idx - O_GW2, 512, 512); src = gW + 1048576; }
    else if (idx < O_NW1) { off = srcoff(idx - O_NW0, 128, 128); src = nW0; }
    else                  { off = srcoff(idx - O_NW1, 128, 128); src = nW; }
    wpk[idx] = f2bf(src[off]);
    return;
  }
  long p = idx - NWS;
  if (p < 1536) { int g = (int)(p >> 9), n = (int)(p & 511);
    int o = (g == 0 ? 0 : (g == 1 ? 1024 : 1536)) + n;
    fpk[F_GB0 + p] = gbi0[o] + gbh0[o]; return; }
  p -= 1536;
  if (p < 1536) { int g = (int)(p >> 9), n = (int)(p & 511);
    int o = (g == 0 ? 0 : (g == 1 ? 1024 : 1536)) + n;
    fpk[F_GB1 + p] = gbi[o] + gbh[o]; return; }
  p -= 1536;
  if (p < 1536) { int g = (int)(p >> 9), n = (int)(p & 511);
    int o = (g == 0 ? 0 : (g == 1 ? 1024 : 1536)) + n;
    fpk[F_GB2 + p] = gbi[2048 + o] + gbh[2048 + o]; return; }
  p -= 1536;
  if (p < 384) { int g = (int)(p / 128), n = (int)(p % 128);
    int o = (g == 0 ? 0 : (g == 1 ? 256 : 384)) + n;
    fpk[F_NB0 + p] = nbi0[o] + nbh0[o]; return; }
  p -= 384;
  if (p < 384) { int g = (int)(p / 128), n = (int)(p % 128);
    int o = (g == 0 ? 0 : (g == 1 ? 256 : 384)) + n;
    fpk[F_NB1 + p] = nbi[o] + nbh[o]; return; }
  p -= 384;
  if (p < 512) { float s = 0.f;
    for (int f = 0; f < 10; ++f) s += eW[f * 512 + p];
    fpk[F_WE + p] = s; return; }
  p -= 512;
  if (p < 128) { fpk[F_AW + p] = aW[p]; return; }
  p -= 128;
  if (p == 0) { float s = 0.f; for (int f = 0; f < 10; ++f) s += eb[f]; fpk[F_BE] = s; return; }
  if (p == 1) { fpk[F_AB] = ab[0]; return; }
}

// LSTM-cell combine from RAW gates (in-kernel scaling; prep stays byte-stable)
__device__ __forceinline__ float cell_h(float gi, float gc, float go) {
  float ei = __builtin_amdgcn_exp2f(gi * -L2E);
  float u  = __builtin_amdgcn_exp2f(gc * (2.0f * L2E));
  float eo = __builtin_amdgcn_exp2f(go * -L2E);
  float r1 = __builtin_amdgcn_rcpf((u + 1.f) * (1.f + ei));
  float cc = (u - 1.f) * r1;
  float s  = cc * cc;
  float num = cc * fmaf(10.f, s, 105.f);
  float den = fmaf(s, s + 45.f, 105.f);
  return num * __builtin_amdgcn_rcpf(den * (1.f + eo));
}

// ---------------- fused main kernel ----------------
// R17: 32x32x16 MFMA CONVERSION. Five scheduling levers (R12-R16) were all
// null/negative -> MFMA(71k) + LDS(58k) + VALU(16k) per CU-gen barely
// overlap and the SUM is the wall. So shrink the terms: 32x32x16 gives
// (a) MFMA pipe 71k->59k (2495 vs 2075 TF ubench efficiency), (b) B-frag
// 1024B per 32768 FLOP (2x less LDS/FLOP) AND CPW=1 (wave owns 1 col-tile,
// both tok-tiles -> a-slab read once not twice): LDS 58k->29k, (c) weights
// still read ONCE per block. acc[3][2] x f32x16 = 96 VGPR; NO ping-pong
// (R12/R14: TLP covers latency, prefetch regs buy nothing) -> ~126 regs
// fits 128-cap at 4 waves/SIMD. WRITE_SIZE ~1.5MB is the spill sentinel.
// LDS activation layout (B-frag order, zero-conflict linear lane*16B):
//   addr(t,k) = (t>>5)*32K + (k>>4)*512 + ((k>>3)&1)*256 + (t&31)*8 + (k&7)
// C/D layout (m74/m101): token = lane&31, n = (r&3) + 8*(r>>2) + 4*(lane>>5).
template <int K, int H, int KOUT, int MODE>
__device__ __forceinline__ void layer32(
    const unsigned short* __restrict__ sIn,
    unsigned short* __restrict__ sOut,
    const unsigned short* __restrict__ wp,
    const float* __restrict__ bias,
    const float* __restrict__ dotw,
    float* accVec,
    int tn, int lane)
{
  constexpr int nKT = K / 16;
  constexpr int nCT = H / 32;
  int hi = lane >> 5;
  floatx16 acc[3][2];
#pragma unroll
  for (int g = 0; g < 3; ++g) {
#pragma unroll
    for (int q = 0; q < 4; ++q) {
      f4 b = *(const f4*)(bias + g * H + tn * 32 + hi * 4 + q * 8);
#pragma unroll
      for (int i = 0; i < 4; ++i) {
        acc[g][0][q * 4 + i] = b[i];
        acc[g][1][q * 4 + i] = b[i];
      }
    }
  }
  const unsigned short* aR = sIn + lane * 8;
  const unsigned short* p0 = wp + (size_t)(0 * nCT + tn) * nKT * 512 + lane * 8;
  const unsigned short* p1 = wp + (size_t)(1 * nCT + tn) * nKT * 512 + lane * 8;
  const unsigned short* p2 = wp + (size_t)(2 * nCT + tn) * nKT * 512 + lane * 8;
#pragma unroll 4
  for (int tk = 0; tk < nKT; ++tk) {
    short8 bb0 = *(const short8*)(aR + tk * 512);
    short8 bb1 = *(const short8*)(aR + tk * 512 + 32 * K);
    short8 a0 = *(const short8*)(p0 + tk * 512);
    short8 a1 = *(const short8*)(p1 + tk * 512);
    short8 a2 = *(const short8*)(p2 + tk * 512);
    acc[0][0] = __builtin_amdgcn_mfma_f32_32x32x16_bf16(a0, bb0, acc[0][0], 0, 0, 0);
    acc[0][1] = __builtin_amdgcn_mfma_f32_32x32x16_bf16(a0, bb1, acc[0][1], 0, 0, 0);
    acc[1][0] = __builtin_amdgcn_mfma_f32_32x32x16_bf16(a1, bb0, acc[1][0], 0, 0, 0);
    acc[1][1] = __builtin_amdgcn_mfma_f32_32x32x16_bf16(a1, bb1, acc[1][1], 0, 0, 0);
    acc[2][0] = __builtin_amdgcn_mfma_f32_32x32x16_bf16(a2, bb0, acc[2][0], 0, 0, 0);
    acc[2][1] = __builtin_amdgcn_mfma_f32_32x32x16_bf16(a2, bb1, acc[2][1], 0, 0, 0);
  }
  if constexpr (MODE == 0) {
#pragma unroll
    for (int tt = 0; tt < 2; ++tt) {
#pragma unroll
      for (int q = 0; q < 4; ++q) {
        ushort4 hw;
        hw.x = f2bf(cell_h(acc[0][tt][q * 4 + 0], acc[1][tt][q * 4 + 0], acc[2][tt][q * 4 + 0]));
        hw.y = f2bf(cell_h(acc[0][tt][q * 4 + 1], acc[1][tt][q * 4 + 1], acc[2][tt][q * 4 + 1]));
        hw.z = f2bf(cell_h(acc[0][tt][q * 4 + 2], acc[1][tt][q * 4 + 2], acc[2][tt][q * 4 + 2]));
        hw.w = f2bf(cell_h(acc[0][tt][q * 4 + 3], acc[1][tt][q * 4 + 3], acc[2][tt][q * 4 + 3]));
        // n0 = tn*32 + hi*4 + q*8 -> ad decomposes with literal q-parts
        int ad = tt * (32 * KOUT) + (tn * 2 + (q >> 1)) * 512 + (q & 1) * 256
               + (lane & 31) * 8 + hi * 4;
        *(ushort4*)&sOut[ad] = hw;
      }
    }
  } else {
#pragma unroll
    for (int tt = 0; tt < 2; ++tt) {
      float v = 0.f;
#pragma unroll
      for (int q = 0; q < 4; ++q) {
        f4 dw = *(const f4*)(dotw + tn * 32 + hi * 4 + q * 8);
#pragma unroll
        for (int i = 0; i < 4; ++i) {
          float h = cell_h(acc[0][tt][q * 4 + i], acc[1][tt][q * 4 + i], acc[2][tt][q * 4 + i]);
          v = fmaf(fmaxf(h, 0.f), dw[i], v);
        }
      }
      v += __shfl_xor(v, 32);   // combine the two n-halves (lane ^ 32, same token)
      if (lane < 32) atomicAdd(&accVec[tt * 32 + (lane & 31)], v);
    }
  }
}

// 1024 threads = 16 waves = 4 waves/SIMD, 1 block/CU (LDS 128.5 KB).
__attribute__((amdgpu_waves_per_eu(4, 4)))
__global__ __launch_bounds__(1024) void dfrnn_main(
    const float* __restrict__ X,
    const unsigned short* __restrict__ wpk,
    const float* __restrict__ fpk,
    float* __restrict__ out)
{
  // B-frag-format buffers: 64 tok x 512 k = 32768 elems each.
  // bufA: X in [0,8192), noise-h in [8192,16384); gL2 output overwrites
  // [0,32768) (X and noise-h dead by then). bufB: gL1 output.
  __shared__ __align__(16) unsigned short bufA[32768];
  __shared__ __align__(16) unsigned short bufB[32768];
  __shared__ float accMu[64];
  __shared__ float accSt[64];
  int tid = threadIdx.x;
  int wave = tid >> 6, lane = tid & 63;
  size_t blkTok = (size_t)blockIdx.x * 64;

  if (tid < 64) { accMu[tid] = 0.f; accSt[tid] = 0.f; }
  // load X tile [64 x 128] fp32 -> bf16 in B-frag (K=128) order,
  // NON-TEMPORAL so streaming X doesn't evict weights from L2 (R9)
  for (int i = tid; i < 64 * 32; i += 1024) {
    int t = i >> 5, c4 = i & 31;
    f4 v = __builtin_nontemporal_load((const f4*)(X + (blkTok + t) * 128 + c4 * 4));
    ushort4 b;
    b.x = f2bf(v.x); b.y = f2bf(v.y); b.z = f2bf(v.z); b.w = f2bf(v.w);
    size_t a = (size_t)(t >> 5) * 4096 + (size_t)(c4 >> 2) * 512
             + (size_t)((c4 >> 1) & 1) * 256 + (size_t)(t & 31) * 8 + (c4 & 1) * 4;
    *(ushort4*)&bufA[a] = b;
  }
  __syncthreads();

  // noise waves {0,5,10,15}: one per SIMD under either wave->SIMD mapping
  bool nact = (wave == 0) | (wave == 5) | (wave == 10) | (wave == 15);
  int ntn = wave / 5;   // 0,5,10,15 -> 0,1,2,3

  // noise L1: X -> noise-h (4 col-tiles of 32, waves {0,5,10,15})
  if (nact)
    layer32<128, 128, 128, 0>(bufA, bufA + 8192, wpk + O_NW0, fpk + F_NB0,
                              nullptr, nullptr, ntn, lane);
  __syncthreads();

  // noise L2: noise-h -> accSt (MODE 1, 4 waves); then gL1: X -> bufB (all)
  if (nact)
    layer32<128, 128, 16, 1>(bufA + 8192, nullptr, wpk + O_NW1, fpk + F_NB1,
                             fpk + F_AW, accSt, ntn, lane);
  layer32<128, 512, 512, 0>(bufA, bufB, wpk + O_GW0, fpk + F_GB0,
                            nullptr, nullptr, wave, lane);
  __syncthreads();

  // gL2: bufB -> bufA (overwrites X + noise-h, both dead)
  layer32<512, 512, 512, 0>(bufB, bufA, wpk + O_GW1, fpk + F_GB1,
                            nullptr, nullptr, wave, lane);
  __syncthreads();

  // gL3: bufA -> accMu (relu-dot with w_e)
  layer32<512, 512, 16, 1>(bufA, nullptr, wpk + O_GW2, fpk + F_GB2,
                           fpk + F_WE, accMu, wave, lane);
  __syncthreads();

  if (tid < 64) {
    float mu = accMu[tid] + fpk[F_BE];
    float st = accSt[tid] + fpk[F_AB];
    out[blkTok + tid] = mu;
    out[NTOK + blkTok + tid] = log1pf(__expf(st)) + 1e-6f;
  }
}

// ---------------- launch ----------------
extern "C" void kernel_launch(void* const* d_in, const int* in_sizes, int n_in,
                              void* d_out, int out_size, void* d_ws, size_t ws_size,
                              hipStream_t stream) {
  const float* X     = (const float*)d_in[0];
  const float* gW0   = (const float*)d_in[1];
  const float* gbi0  = (const float*)d_in[2];
  const float* gbh0  = (const float*)d_in[3];
  const float* gW    = (const float*)d_in[4];
  const float* gbi   = (const float*)d_in[5];
  const float* gbh   = (const float*)d_in[6];
  const float* eW    = (const float*)d_in[7];
  const float* eb    = (const float*)d_in[8];
  const float* nW0   = (const float*)d_in[9];
  const float* nbi0  = (const float*)d_in[10];
  const float* nbh0  = (const float*)d_in[11];
  const float* nW    = (const float*)d_in[12];
  const float* nbi   = (const float*)d_in[13];
  const float* nbh   = (const float*)d_in[14];
  const float* aW    = (const float*)d_in[15];
  const float* ab    = (const float*)d_in[16];

  unsigned short* wpk = (unsigned short*)d_ws;
  float* fpk = (float*)((char*)d_ws + NWS * 2);

  long prepTotal = NWS + 1536 * 3 + 384 * 2 + 512 + 128 + 2;
  int prepBlocks = (int)((prepTotal + 255) / 256);
  prep_kernel<<<prepBlocks, 256, 0, stream>>>(gW0, gbi0, gbh0, gW, gbi, gbh, eW, eb,
                                              nW0, nbi0, nbh0, nW, nbi, nbh, aW, ab,
                                              wpk, fpk);
  dfrnn_main<<<3072, 1024, 0, stream>>>(X, wpk, fpk, (float*)d_out);
}